// Round 2
// baseline (149.466 us; speedup 1.0000x reference)
//
#include <hip/hip_runtime.h>

#define F_ALPHA 0.25f
#define F_EPS   1e-8f

constexpr int B = 8, N = 16384, C = 80, M = 100;
constexpr int NT = 128;          // n per block
constexpr int THREADS = 256;     // 4 waves
constexpr int MPW = 25;          // m per wave (4 waves x 25 = 100)
constexpr int LDC = 84;          // padded LDS stride: /4=21 odd -> conflict-free b128 row reads

// ws layout (bytes):
//   ct_f   : B*M*C floats  = 256000   @ 0
//   b2area : B*M   floats  =   3200   @ 256000
//   clsid  : B*M   ints    =   3200   @ 259200
//   packed : B*M   u64     =   6400   @ 262400  (8-aligned)
constexpr size_t WS_CT   = 0;
constexpr size_t WS_A2   = 256000;
constexpr size_t WS_CID  = 259200;
constexpr size_t WS_PACK = 262400;

__device__ __forceinline__ unsigned ford(float f) {
    unsigned u = __float_as_uint(f);
    return (u & 0x80000000u) ? ~u : (u | 0x80000000u);
}

__device__ __forceinline__ float pair_total(float cls,
    float py0, float px0, float py1, float px1,
    float ty0, float tx0, float ty1, float tx1,
    float a1, float a2)
{
    float ih = fminf(py1, ty1) - fmaxf(py0, ty0);
    float iw = fminf(px1, tx1) - fmaxf(px0, tx0);
    float inter = fmaxf(ih, 0.f) * fmaxf(iw, 0.f);
    float uni = a1 + a2 - inter;
    float iou = (uni > 0.f) ? (inter / uni) : 0.f;
    float eh = fmaxf(py1, ty1) - fminf(py0, ty0);
    float ew = fmaxf(px1, tx1) - fminf(px0, tx0);
    float enc = fmaxf(eh, 0.f) * fmaxf(ew, 0.f);
    float g = iou - ((enc > 0.f) ? ((enc - uni) / enc) : 0.f);
    float gl = 1.f - g;
    float rg = fabsf(ty0 - py0) + fabsf(tx0 - px0) +
               fabsf(ty1 - py1) + fabsf(tx1 - px1);
    return 2.f * cls + 5.f * rg + 2.f * gl;
}

__global__ void prep_kernel(const int* __restrict__ cls_true,
                            const float* __restrict__ loc_true,
                            float* __restrict__ ct_f,
                            float* __restrict__ b2area,
                            int* __restrict__ clsid,
                            unsigned long long* __restrict__ packed)
{
    int idx = blockIdx.x * blockDim.x + threadIdx.x;
    if (idx >= B * M) return;
    int cid = 0;
    bool found = false;
    for (int c = 0; c < C; ++c) {
        int v = cls_true[idx * C + c];
        float f = (v == 1) ? 1.0f : 0.0f;
        ct_f[idx * C + c] = f;
        if (!found && v == 1) { cid = c; found = true; }
    }
    clsid[idx] = cid;
    float y0 = loc_true[idx * 4 + 0], x0 = loc_true[idx * 4 + 1];
    float y1 = loc_true[idx * 4 + 2], x1 = loc_true[idx * 4 + 3];
    b2area[idx] = fmaxf(y1 - y0, 0.f) * fmaxf(x1 - x0, 0.f);
    packed[idx] = 0xFFFFFFFFFFFFFFFFull;
}

__global__ __launch_bounds__(THREADS, 3)
void match_kernel(const float* __restrict__ cls_pred,
                  const float* __restrict__ loc_pred,
                  const float* __restrict__ ct_f,
                  const float* __restrict__ loc_true,
                  const float* __restrict__ b2area,
                  unsigned long long* __restrict__ packed)
{
    __shared__ float s_diff[NT][LDC];   // 128*84*4 = 43008 B
    __shared__ float s_lt[M][4];
    __shared__ float s_a2[M];

    const int b  = blockIdx.y;
    const int n0 = blockIdx.x * NT;
    const int t  = threadIdx.x;
    const int l  = t & 63;       // lane
    // wave id, forced wave-uniform so ct addresses scalarize to s_load
    const int wu = __builtin_amdgcn_readfirstlane(t >> 6);

    // ---- stage diff = pos_cost - neg_cost into LDS ----
    const float4* cp4 = (const float4*)(cls_pred + ((size_t)b * N + n0) * C);
    for (int i = t; i < NT * C / 4; i += THREADS) {
        float4 v = cp4[i];
        int e = i * 4;
        int nl = e / C, c = e % C;
        float pv[4] = { v.x, v.y, v.z, v.w };
        #pragma unroll
        for (int j = 0; j < 4; ++j) {
            float p = pv[j];
            float q = 1.0f - p;
            float pos = F_ALPHA * q * q * (-logf(p + F_EPS));
            float neg = (1.0f - F_ALPHA) * p * p * (-logf(q + F_EPS));
            s_diff[nl][c + j] = pos - neg;
        }
    }
    // ---- stage loc_true + areas ----
    for (int i = t; i < M * 4; i += THREADS) {
        s_lt[i / 4][i % 4] = loc_true[(size_t)b * M * 4 + i];
    }
    for (int i = t; i < M; i += THREADS) {
        s_a2[i] = b2area[(size_t)b * M + i];
    }
    __syncthreads();

    // ---- per-lane n pair ----
    const int nA = n0 + l;
    const int nB = n0 + l + 64;
    float4 lpA = ((const float4*)loc_pred)[(size_t)b * N + nA];
    float4 lpB = ((const float4*)loc_pred)[(size_t)b * N + nB];
    float a1A = fmaxf(lpA.z - lpA.x, 0.f) * fmaxf(lpA.w - lpA.y, 0.f);
    float a1B = fmaxf(lpB.z - lpB.x, 0.f) * fmaxf(lpB.w - lpB.y, 0.f);

    float acc[MPW][2];
    #pragma unroll
    for (int j = 0; j < MPW; ++j) { acc[j][0] = 0.f; acc[j][1] = 0.f; }

    // uniform base for this batch's ct (wave-uniform -> scalar loads)
    const float* ctb = ct_f + (size_t)b * M * C;

    for (int c0 = 0; c0 < C; c0 += 4) {
        float4 dA = *(const float4*)&s_diff[l][c0];
        float4 dB = *(const float4*)&s_diff[l + 64][c0];
        #pragma unroll
        for (int j = 0; j < MPW; ++j) {
            const int m = wu + 4 * j;
            float4 ct4 = *(const float4*)&ctb[m * C + c0];  // uniform addr -> s_load_dwordx4
            acc[j][0] = fmaf(dA.x, ct4.x, acc[j][0]);
            acc[j][0] = fmaf(dA.y, ct4.y, acc[j][0]);
            acc[j][0] = fmaf(dA.z, ct4.z, acc[j][0]);
            acc[j][0] = fmaf(dA.w, ct4.w, acc[j][0]);
            acc[j][1] = fmaf(dB.x, ct4.x, acc[j][1]);
            acc[j][1] = fmaf(dB.y, ct4.y, acc[j][1]);
            acc[j][1] = fmaf(dB.z, ct4.z, acc[j][1]);
            acc[j][1] = fmaf(dB.w, ct4.w, acc[j][1]);
        }
    }

    // ---- epilogue: totals, pack, wave-reduce argmin, atomic ----
    #pragma unroll
    for (int j = 0; j < MPW; ++j) {
        const int m = wu + 4 * j;
        float ty0 = s_lt[m][0], tx0 = s_lt[m][1];
        float ty1 = s_lt[m][2], tx1 = s_lt[m][3];
        float a2  = s_a2[m];
        float totA = pair_total(acc[j][0], lpA.x, lpA.y, lpA.z, lpA.w,
                                ty0, tx0, ty1, tx1, a1A, a2);
        float totB = pair_total(acc[j][1], lpB.x, lpB.y, lpB.z, lpB.w,
                                ty0, tx0, ty1, tx1, a1B, a2);
        unsigned long long pA = (((unsigned long long)ford(totA)) << 32) | (unsigned)nA;
        unsigned long long pB = (((unsigned long long)ford(totB)) << 32) | (unsigned)nB;
        unsigned long long pmin = (pA < pB) ? pA : pB;
        #pragma unroll
        for (int off = 32; off >= 1; off >>= 1) {
            unsigned long long other = __shfl_xor(pmin, off, 64);
            if (other < pmin) pmin = other;
        }
        if (l == 0) {
            atomicMin(&packed[(size_t)b * M + m], pmin);
        }
    }
}

__global__ void out_kernel(const unsigned long long* __restrict__ packed,
                           const int* __restrict__ clsid,
                           int* __restrict__ out)
{
    int idx = blockIdx.x * blockDim.x + threadIdx.x;
    if (idx >= B * M) return;
    int b = idx / M;
    out[idx * 3 + 0] = b;
    out[idx * 3 + 1] = (int)(unsigned)(packed[idx] & 0xFFFFFFFFull);
    out[idx * 3 + 2] = clsid[idx];
}

extern "C" void kernel_launch(void* const* d_in, const int* in_sizes, int n_in,
                              void* d_out, int out_size, void* d_ws, size_t ws_size,
                              hipStream_t stream)
{
    const float* cls_pred = (const float*)d_in[0];
    const float* loc_pred = (const float*)d_in[1];
    const int*   cls_true = (const int*)d_in[2];
    const float* loc_true = (const float*)d_in[3];
    // d_in[4] = reg_mask (unused by the reference output)

    char* ws = (char*)d_ws;
    float* ct_f   = (float*)(ws + WS_CT);
    float* b2area = (float*)(ws + WS_A2);
    int*   clsid  = (int*)(ws + WS_CID);
    unsigned long long* packed = (unsigned long long*)(ws + WS_PACK);

    int* out = (int*)d_out;

    prep_kernel<<<(B * M + 255) / 256, 256, 0, stream>>>(
        cls_true, loc_true, ct_f, b2area, clsid, packed);

    dim3 grid(N / NT, B);
    match_kernel<<<grid, THREADS, 0, stream>>>(
        cls_pred, loc_pred, ct_f, loc_true, b2area, packed);

    out_kernel<<<(B * M + 255) / 256, 256, 0, stream>>>(packed, clsid, out);
}

// Round 3
// 130.021 us; speedup vs baseline: 1.1495x; 1.1495x over previous
//
#include <hip/hip_runtime.h>

#define F_ALPHA 0.25f
#define F_EPS   1e-8f

constexpr int B = 8, N = 16384, C = 80, M = 100;
constexpr int NT = 128;          // n per block
constexpr int THREADS = 256;     // 4 waves; wave w owns m = w*25 .. w*25+24
constexpr int LDC = 84;          // diff LDS stride (floats): 16B-aligned rows, balanced banks

// ws layout (bytes):
//   masks  : [B][3][112] u32 = 10752 @ 0      (chunk-major, m padded 100->112: idx = (m/25)*28 + m%25)
//   b2area : B*M floats      =  3200 @ 10752
//   clsid  : B*M ints        =  3200 @ 13952
//   packed : B*M u64         =  6400 @ 17152  (8-aligned)
constexpr size_t WS_MASK = 0;
constexpr size_t WS_A2   = 10752;
constexpr size_t WS_CID  = 13952;
constexpr size_t WS_PACK = 17152;

__device__ __forceinline__ unsigned ford(float f) {
    unsigned u = __float_as_uint(f);
    return (u & 0x80000000u) ? ~u : (u | 0x80000000u);
}

__device__ __forceinline__ float rcpf(float x) { return __builtin_amdgcn_rcpf(x); }

__device__ __forceinline__ float pair_total(float cls,
    float py0, float px0, float py1, float px1,
    float ty0, float tx0, float ty1, float tx1,
    float a1, float a2)
{
    float ih = fminf(py1, ty1) - fmaxf(py0, ty0);
    float iw = fminf(px1, tx1) - fmaxf(px0, tx0);
    float inter = fmaxf(ih, 0.f) * fmaxf(iw, 0.f);
    float uni = a1 + a2 - inter;
    float ip = (uni > 0.f) ? inter * rcpf(uni) : 0.f;       // iou
    float eh = fmaxf(py1, ty1) - fminf(py0, ty0);
    float ew = fmaxf(px1, tx1) - fminf(px0, tx0);
    float enc = fmaxf(eh, 0.f) * fmaxf(ew, 0.f);
    float ue = (enc > 0.f) ? (1.f - uni * rcpf(enc)) : 0.f; // (enc-uni)/enc
    float one_m_giou = 1.f - ip + ue;
    float rg = fabsf(ty0 - py0) + fabsf(tx0 - px0) +
               fabsf(ty1 - py1) + fabsf(tx1 - px1);
    return 2.f * cls + 5.f * rg + 2.f * one_m_giou;
}

// Per-(m) epilogue: totals for the lane's two n's, pack, wave argmin, one atomic.
// __noinline__ keeps the 25x-unrolled caller small (I-cache).
__device__ __noinline__ void epi_reduce(float cA, float cB,
    float ty0, float tx0, float ty1, float tx1, float a2,
    float pAy0, float pAx0, float pAy1, float pAx1, float a1A,
    float pBy0, float pBx0, float pBy1, float pBx1, float a1B,
    int nA, int nB, unsigned long long* slot)
{
    float totA = pair_total(cA, pAy0, pAx0, pAy1, pAx1, ty0, tx0, ty1, tx1, a1A, a2);
    float totB = pair_total(cB, pBy0, pBx0, pBy1, pBx1, ty0, tx0, ty1, tx1, a1B, a2);
    unsigned long long pA = ((unsigned long long)ford(totA) << 32) | (unsigned)nA;
    unsigned long long pB = ((unsigned long long)ford(totB) << 32) | (unsigned)nB;
    unsigned long long pmin = (pA < pB) ? pA : pB;
    #pragma unroll
    for (int off = 32; off >= 1; off >>= 1) {
        unsigned long long o = __shfl_xor(pmin, off, 64);
        if (o < pmin) pmin = o;
    }
    if ((threadIdx.x & 63) == 0) atomicMin(slot, pmin);
}

// One wave per (b,m): ballot-built bitmasks, clsid, area, packed init.
__global__ void prep_kernel(const int* __restrict__ cls_true,
                            const float* __restrict__ loc_true,
                            unsigned* __restrict__ masks,
                            float* __restrict__ b2area,
                            int* __restrict__ clsid,
                            unsigned long long* __restrict__ packed)
{
    int wid = (blockIdx.x * blockDim.x + threadIdx.x) >> 6;
    int l = threadIdx.x & 63;
    if (wid >= B * M) return;
    const int* row = cls_true + (size_t)wid * C;
    bool v1 = (row[l] == 1);                      // c = 0..63
    bool v2 = (l < 16) ? (row[64 + l] == 1) : false; // c = 64..79
    unsigned long long m01 = __ballot(v1);
    unsigned long long m2  = __ballot(v2);
    if (l == 0) {
        int b = wid / M, m = wid % M;
        unsigned* mb = masks + b * 336 + (m / 25) * 28 + (m % 25);
        mb[0]   = (unsigned)m01;
        mb[112] = (unsigned)(m01 >> 32);
        mb[224] = (unsigned)m2;
        int cid = 0;
        if (m01) cid = __ffsll(m01) - 1;
        else if (m2) cid = 64 + __ffsll(m2) - 1;
        clsid[wid] = cid;
        float y0 = loc_true[wid * 4 + 0], x0 = loc_true[wid * 4 + 1];
        float y1 = loc_true[wid * 4 + 2], x1 = loc_true[wid * 4 + 3];
        b2area[wid] = fmaxf(y1 - y0, 0.f) * fmaxf(x1 - x0, 0.f);
        packed[wid] = 0xFFFFFFFFFFFFFFFFull;
    }
}

__global__ __launch_bounds__(THREADS, 3)
void match_kernel(const float* __restrict__ cls_pred,
                  const float* __restrict__ loc_pred,
                  const unsigned* __restrict__ masks,
                  const float* __restrict__ loc_true,
                  const float* __restrict__ b2area,
                  unsigned long long* __restrict__ packed)
{
    __shared__ float s_diff[NT][LDC];   // 43008 B
    __shared__ float s_lt[M][4];
    __shared__ float s_a2[M];

    const int b  = blockIdx.y;
    const int n0 = blockIdx.x * NT;
    const int t  = threadIdx.x;
    const int l  = t & 63;
    const int wu = __builtin_amdgcn_readfirstlane(t >> 6);  // wave id, SGPR

    // ---- stage diff = pos_cost - neg_cost into LDS (float4 in/out) ----
    const float4* cp4 = (const float4*)(cls_pred + ((size_t)b * N + n0) * C);
    for (int i = t; i < NT * C / 4; i += THREADS) {
        float4 v = cp4[i];
        int e = i * 4, nl = e / C, c = e % C;
        float pv[4] = { v.x, v.y, v.z, v.w };
        float ov[4];
        #pragma unroll
        for (int j = 0; j < 4; ++j) {
            float p = pv[j], q = 1.0f - p;
            float pos = F_ALPHA * q * q * (-logf(p + F_EPS));
            float neg = (1.0f - F_ALPHA) * p * p * (-logf(q + F_EPS));
            ov[j] = pos - neg;
        }
        *(float4*)&s_diff[nl][c] = make_float4(ov[0], ov[1], ov[2], ov[3]);
    }
    for (int i = t; i < M * 4; i += THREADS)
        s_lt[i / 4][i % 4] = loc_true[(size_t)b * M * 4 + i];
    for (int i = t; i < M; i += THREADS)
        s_a2[i] = b2area[(size_t)b * M + i];
    __syncthreads();

    // ---- per-lane n pair ----
    const int nA = n0 + l;
    const int nB = nA + 64;
    float4 lpA = ((const float4*)loc_pred)[(size_t)b * N + nA];
    float4 lpB = ((const float4*)loc_pred)[(size_t)b * N + nB];
    float a1A = fmaxf(lpA.z - lpA.x, 0.f) * fmaxf(lpA.w - lpA.y, 0.f);
    float a1B = fmaxf(lpB.z - lpB.x, 0.f) * fmaxf(lpB.w - lpB.y, 0.f);

    float acc[25][2];
    #pragma unroll
    for (int j = 0; j < 25; ++j) { acc[j][0] = 0.f; acc[j][1] = 0.f; }

    const unsigned* mb = masks + b * 336 + wu * 28;

    for (int ch = 0; ch < 3; ++ch) {
        // 28 bitmasks for this wave's 25 m's (this 32-c chunk) -> SGPRs
        unsigned mm[28];
        #pragma unroll
        for (int q = 0; q < 7; ++q) {
            uint4 v = ((const uint4*)(mb + (size_t)ch * 112))[q];
            mm[q * 4 + 0] = (unsigned)__builtin_amdgcn_readfirstlane((int)v.x);
            mm[q * 4 + 1] = (unsigned)__builtin_amdgcn_readfirstlane((int)v.y);
            mm[q * 4 + 2] = (unsigned)__builtin_amdgcn_readfirstlane((int)v.z);
            mm[q * 4 + 3] = (unsigned)__builtin_amdgcn_readfirstlane((int)v.w);
        }
        const int nc0 = (ch == 2) ? 4 : 8;   // chunk 2 covers c=64..79 only
        for (int c0 = 0; c0 < nc0; ++c0) {
            const int cb = ch * 32 + c0 * 4;
            float4 dA = *(const float4*)&s_diff[l][cb];
            float4 dB = *(const float4*)&s_diff[l + 64][cb];
            #pragma unroll
            for (int j = 0; j < 25; ++j) {
                unsigned sm = mm[j] >> (c0 * 4);           // uniform: SALU
                float f0 = (sm & 1u) ? 1.0f : 0.0f;        // s_cselect -> SGPR
                float f1 = (sm & 2u) ? 1.0f : 0.0f;
                float f2 = (sm & 4u) ? 1.0f : 0.0f;
                float f3 = (sm & 8u) ? 1.0f : 0.0f;
                acc[j][0] = fmaf(f0, dA.x, acc[j][0]);
                acc[j][0] = fmaf(f1, dA.y, acc[j][0]);
                acc[j][0] = fmaf(f2, dA.z, acc[j][0]);
                acc[j][0] = fmaf(f3, dA.w, acc[j][0]);
                acc[j][1] = fmaf(f0, dB.x, acc[j][1]);
                acc[j][1] = fmaf(f1, dB.y, acc[j][1]);
                acc[j][1] = fmaf(f2, dB.z, acc[j][1]);
                acc[j][1] = fmaf(f3, dB.w, acc[j][1]);
            }
        }
    }

    // ---- epilogue ----
    #pragma unroll
    for (int j = 0; j < 25; ++j) {
        const int m = wu * 25 + j;
        epi_reduce(acc[j][0], acc[j][1],
                   s_lt[m][0], s_lt[m][1], s_lt[m][2], s_lt[m][3], s_a2[m],
                   lpA.x, lpA.y, lpA.z, lpA.w, a1A,
                   lpB.x, lpB.y, lpB.z, lpB.w, a1B,
                   nA, nB, &packed[(size_t)b * M + m]);
    }
}

__global__ void out_kernel(const unsigned long long* __restrict__ packed,
                           const int* __restrict__ clsid,
                           int* __restrict__ out)
{
    int idx = blockIdx.x * blockDim.x + threadIdx.x;
    if (idx >= B * M) return;
    int b = idx / M;
    out[idx * 3 + 0] = b;
    out[idx * 3 + 1] = (int)(unsigned)(packed[idx] & 0xFFFFFFFFull);
    out[idx * 3 + 2] = clsid[idx];
}

extern "C" void kernel_launch(void* const* d_in, const int* in_sizes, int n_in,
                              void* d_out, int out_size, void* d_ws, size_t ws_size,
                              hipStream_t stream)
{
    const float* cls_pred = (const float*)d_in[0];
    const float* loc_pred = (const float*)d_in[1];
    const int*   cls_true = (const int*)d_in[2];
    const float* loc_true = (const float*)d_in[3];
    // d_in[4] = reg_mask (unused by the reference output)

    char* ws = (char*)d_ws;
    unsigned* masks = (unsigned*)(ws + WS_MASK);
    float* b2area   = (float*)(ws + WS_A2);
    int*   clsid    = (int*)(ws + WS_CID);
    unsigned long long* packed = (unsigned long long*)(ws + WS_PACK);

    int* out = (int*)d_out;

    prep_kernel<<<(B * M * 64 + 255) / 256, 256, 0, stream>>>(
        cls_true, loc_true, masks, b2area, clsid, packed);

    dim3 grid(N / NT, B);
    match_kernel<<<grid, THREADS, 0, stream>>>(
        cls_pred, loc_pred, masks, loc_true, b2area, packed);

    out_kernel<<<(B * M + 255) / 256, 256, 0, stream>>>(packed, clsid, out);
}

// Round 4
// 55.014 us; speedup vs baseline: 2.7169x; 2.3634x over previous
//
#include <hip/hip_runtime.h>

constexpr int B = 8, N = 16384, C = 80, M = 100;
constexpr int NT = 128;          // n per block
constexpr int THREADS = 256;     // 4 waves; wave owns 32 n (2 row-frags)
constexpr int LDA = 104;         // fp16 stride for A tiles (208B = 13*16B, conflict-benign)

typedef _Float16 half8 __attribute__((ext_vector_type(8)));
typedef _Float16 half4 __attribute__((ext_vector_type(4)));
typedef float f32x4 __attribute__((ext_vector_type(4)));

// ws layout (bytes):
//   ftab   : [B][3][7][64] uint4 = 172032 @ 0     (ct as packed fp16 B-fragments)
//   clsid  : B*M ints            =   3200 @ 172032
//   packed : B*M u64             =   6400 @ 175232 (8-aligned)
constexpr size_t WS_FTAB = 0;
constexpr size_t WS_CID  = 172032;
constexpr size_t WS_PACK = 175232;

__device__ __forceinline__ unsigned ford(float f) {
    unsigned u = __float_as_uint(f);
    return (u & 0x80000000u) ? ~u : (u | 0x80000000u);
}

__device__ __forceinline__ float rcpf(float x) { return __builtin_amdgcn_rcpf(x); }

__device__ __forceinline__ float pair_total(float cls,
    float4 p, float4 t, float a1, float a2)
{
    // boxes: [ymin, xmin, ymax, xmax] = (x,y,z,w)
    float ih = fminf(p.z, t.z) - fmaxf(p.x, t.x);
    float iw = fminf(p.w, t.w) - fmaxf(p.y, t.y);
    float inter = fmaxf(ih, 0.f) * fmaxf(iw, 0.f);
    float uni = a1 + a2 - inter;
    float iou = (uni > 0.f) ? inter * rcpf(uni) : 0.f;
    float eh = fmaxf(p.z, t.z) - fminf(p.x, t.x);
    float ew = fmaxf(p.w, t.w) - fminf(p.y, t.y);
    float enc = fmaxf(eh, 0.f) * fmaxf(ew, 0.f);
    float ue = (enc > 0.f) ? (1.f - uni * rcpf(enc)) : 0.f;   // (enc-uni)/enc
    float one_m_giou = 1.f - iou + ue;
    float rg = fabsf(t.x - p.x) + fabsf(t.y - p.y) +
               fabsf(t.z - p.z) + fabsf(t.w - p.w);
    return 2.f * cls + 5.f * rg + 2.f * one_m_giou;
}

// Build ct fp16 B-fragment table: frag f = ((b*3 + ch)*7 + mf), lane l holds
// B[k = ch*32 + (l>>4)*8 + e][col = m = mf*16 + (l&15)] as packed fp16 pairs.
__global__ void prep_frag(const int* __restrict__ cls_true, uint4* __restrict__ ftab)
{
    int tid = blockIdx.x * blockDim.x + threadIdx.x;
    int f = tid >> 6, l = tid & 63;
    if (f >= B * 21) return;
    int b = f / 21, rem = f % 21, ch = rem / 7, mf = rem % 7;
    int m = mf * 16 + (l & 15);
    int c0 = ch * 32 + (l >> 4) * 8;
    unsigned w[4] = {0, 0, 0, 0};
    if (m < M) {
        const int* row = cls_true + ((size_t)b * M + m) * C;
        #pragma unroll
        for (int e = 0; e < 8; ++e) {
            int c = c0 + e;
            unsigned h = (c < C && row[c] == 1) ? 0x3C00u : 0u;  // fp16 1.0
            w[e >> 1] |= h << ((e & 1) * 16);
        }
    }
    ftab[(size_t)f * 64 + l] = make_uint4(w[0], w[1], w[2], w[3]);
}

// One wave per (b,m): clsid via ballot + packed init.
__global__ void prep_misc(const int* __restrict__ cls_true,
                          int* __restrict__ clsid,
                          unsigned long long* __restrict__ packed)
{
    int wid = (blockIdx.x * blockDim.x + threadIdx.x) >> 6;
    int l = threadIdx.x & 63;
    if (wid >= B * M) return;
    const int* row = cls_true + (size_t)wid * C;
    bool v1 = (row[l] == 1);
    bool v2 = (l < 16) ? (row[64 + l] == 1) : false;
    unsigned long long m01 = __ballot(v1);
    unsigned long long m2  = __ballot(v2);
    if (l == 0) {
        int cid = 0;
        if (m01) cid = __ffsll(m01) - 1;
        else if (m2) cid = 64 + __ffsll(m2) - 1;
        clsid[wid] = cid;
        packed[wid] = 0xFFFFFFFFFFFFFFFFull;
    }
}

__global__ __launch_bounds__(THREADS, 2)
void match_kernel(const float* __restrict__ cls_pred,
                  const float* __restrict__ loc_pred,
                  const uint4* __restrict__ ftab,
                  const float* __restrict__ loc_true,
                  unsigned long long* __restrict__ packed)
{
    __shared__ _Float16 s_hi[NT][LDA];            // 26624 B
    __shared__ _Float16 s_lo[NT][LDA];            // 26624 B
    __shared__ float s_lp[NT][4];                 //  2048 B
    __shared__ float s_lt[112][4];                //  1792 B
    __shared__ unsigned long long s_red[4][112];  //  3584 B

    const int b  = blockIdx.y;
    const int n0 = blockIdx.x * NT;
    const int t  = threadIdx.x;
    const int l  = t & 63;
    const int wv = t >> 6;

    // ---- stage diff = pos-neg as fp16 hi + lo*2^-11 split ----
    const float4* cp4 = (const float4*)(cls_pred + ((size_t)b * N + n0) * C);
    for (int i = t; i < NT * C / 4; i += THREADS) {
        float4 v = cp4[i];
        int e = i * 4, nl = e / C, c = e % C;
        float pv[4] = { v.x, v.y, v.z, v.w };
        half4 hh, ll;
        #pragma unroll
        for (int j = 0; j < 4; ++j) {
            float p = pv[j], q = 1.0f - p;
            float pos = 0.25f * q * q * (-__logf(p + 1e-8f));
            float neg = 0.75f * p * p * (-__logf(q + 1e-8f));
            float d = pos - neg;
            _Float16 h = (_Float16)d;
            float rs = (d - (float)h) * 2048.0f;   // keep lo normal in fp16
            hh[j] = h;
            ll[j] = (_Float16)rs;
        }
        *(half4*)&s_hi[nl][c] = hh;
        *(half4*)&s_lo[nl][c] = ll;
    }
    // zero-pad c in [80,96)
    for (int i = t; i < NT * 16 / 4; i += THREADS) {
        int nl = i >> 2, c = C + (i & 3) * 4;
        half4 z = {0, 0, 0, 0};
        *(half4*)&s_hi[nl][c] = z;
        *(half4*)&s_lo[nl][c] = z;
    }
    // boxes
    if (t < NT) {
        *(float4*)&s_lp[t][0] = ((const float4*)loc_pred)[(size_t)b * N + n0 + t];
    } else if (t < NT + 112) {
        int m = t - NT;
        float4 tb = (m < M) ? ((const float4*)loc_true)[(size_t)b * M + m]
                            : make_float4(0.f, 0.f, 0.f, 0.f);
        *(float4*)&s_lt[m][0] = tb;
    }
    __syncthreads();

    // ---- MFMA: D[n][m] = diff(n,c) . ct(c,m), fp16 2-split, one fp32 acc ----
    const int nw = wv * 32;
    f32x4 acc[2][7];
    #pragma unroll
    for (int nf = 0; nf < 2; ++nf)
        #pragma unroll
        for (int mf = 0; mf < 7; ++mf)
            acc[nf][mf] = f32x4{0.f, 0.f, 0.f, 0.f};

    const uint4* ft = ftab + (size_t)b * 21 * 64;
    const int arow = nw + (l & 15);
    const int acol = (l >> 4) * 8;

    #pragma unroll
    for (int kc = 0; kc < 3; ++kc) {
        half8 ah0 = *(const half8*)&s_hi[arow][kc * 32 + acol];
        half8 ah1 = *(const half8*)&s_hi[arow + 16][kc * 32 + acol];
        half8 al0 = *(const half8*)&s_lo[arow][kc * 32 + acol];
        half8 al1 = *(const half8*)&s_lo[arow + 16][kc * 32 + acol];
        #pragma unroll
        for (int mf = 0; mf < 7; ++mf) {
            union { uint4 u; half8 h; } b1, b2;
            b1.u = ft[((size_t)kc * 7 + mf) * 64 + l];
            b2.u = make_uint4(b1.u.x & 0x10001000u, b1.u.y & 0x10001000u,
                              b1.u.z & 0x10001000u, b1.u.w & 0x10001000u); // ct * 2^-11
            acc[0][mf] = __builtin_amdgcn_mfma_f32_16x16x32_f16(ah0, b1.h, acc[0][mf], 0, 0, 0);
            acc[1][mf] = __builtin_amdgcn_mfma_f32_16x16x32_f16(ah1, b1.h, acc[1][mf], 0, 0, 0);
            acc[0][mf] = __builtin_amdgcn_mfma_f32_16x16x32_f16(al0, b2.h, acc[0][mf], 0, 0, 0);
            acc[1][mf] = __builtin_amdgcn_mfma_f32_16x16x32_f16(al1, b2.h, acc[1][mf], 0, 0, 0);
        }
    }

    // ---- epilogue: per-lane 8 n-boxes (4 rows x 2 nf), per-mf m-box ----
    float4 bx[2][4];
    float a1[2][4];
    #pragma unroll
    for (int nf = 0; nf < 2; ++nf)
        #pragma unroll
        for (int r = 0; r < 4; ++r) {
            int row = nw + nf * 16 + (l >> 4) * 4 + r;
            float4 v = *(const float4*)&s_lp[row][0];
            bx[nf][r] = v;
            a1[nf][r] = fmaxf(v.z - v.x, 0.f) * fmaxf(v.w - v.y, 0.f);
        }

    #pragma unroll
    for (int mf = 0; mf < 7; ++mf) {
        float4 tb = *(const float4*)&s_lt[mf * 16 + (l & 15)][0];
        float a2 = fmaxf(tb.z - tb.x, 0.f) * fmaxf(tb.w - tb.y, 0.f);
        unsigned long long cand = 0xFFFFFFFFFFFFFFFFull;
        #pragma unroll
        for (int nf = 0; nf < 2; ++nf)
            #pragma unroll
            for (int r = 0; r < 4; ++r) {
                float tot = pair_total(acc[nf][mf][r], bx[nf][r], tb, a1[nf][r], a2);
                int n = n0 + nw + nf * 16 + (l >> 4) * 4 + r;
                unsigned long long key =
                    ((unsigned long long)ford(tot) << 32) | (unsigned)n;
                cand = (key < cand) ? key : cand;
            }
        // combine the 4 row-groups (lanes differing in bits 4,5) -> per-m min
        #pragma unroll
        for (int off = 16; off <= 32; off <<= 1) {
            unsigned long long o = __shfl_xor(cand, off, 64);
            if (o < cand) cand = o;
        }
        if (l < 16) s_red[wv][mf * 16 + l] = cand;
    }
    __syncthreads();

    // ---- block reduce + one atomic per m ----
    if (t < 112) {
        unsigned long long v0 = s_red[0][t], v1 = s_red[1][t];
        unsigned long long v2 = s_red[2][t], v3 = s_red[3][t];
        unsigned long long a = v0 < v1 ? v0 : v1;
        unsigned long long c2 = v2 < v3 ? v2 : v3;
        a = a < c2 ? a : c2;
        if (t < M) atomicMin(&packed[(size_t)b * M + t], a);
    }
}

__global__ void out_kernel(const unsigned long long* __restrict__ packed,
                           const int* __restrict__ clsid,
                           int* __restrict__ out)
{
    int idx = blockIdx.x * blockDim.x + threadIdx.x;
    if (idx >= B * M) return;
    int b = idx / M;
    out[idx * 3 + 0] = b;
    out[idx * 3 + 1] = (int)(unsigned)(packed[idx] & 0xFFFFFFFFull);
    out[idx * 3 + 2] = clsid[idx];
}

extern "C" void kernel_launch(void* const* d_in, const int* in_sizes, int n_in,
                              void* d_out, int out_size, void* d_ws, size_t ws_size,
                              hipStream_t stream)
{
    const float* cls_pred = (const float*)d_in[0];
    const float* loc_pred = (const float*)d_in[1];
    const int*   cls_true = (const int*)d_in[2];
    const float* loc_true = (const float*)d_in[3];
    // d_in[4] = reg_mask (unused by the reference output)

    char* ws = (char*)d_ws;
    uint4* ftab = (uint4*)(ws + WS_FTAB);
    int*   clsid = (int*)(ws + WS_CID);
    unsigned long long* packed = (unsigned long long*)(ws + WS_PACK);

    int* out = (int*)d_out;

    prep_frag<<<(B * 21 * 64 + 255) / 256, 256, 0, stream>>>(cls_true, ftab);
    prep_misc<<<(B * M * 64 + 255) / 256, 256, 0, stream>>>(cls_true, clsid, packed);

    dim3 grid(N / NT, B);
    match_kernel<<<grid, THREADS, 0, stream>>>(
        cls_pred, loc_pred, ftab, loc_true, packed);

    out_kernel<<<(B * M + 255) / 256, 256, 0, stream>>>(packed, clsid, out);
}